// Round 1
// baseline (2831.614 us; speedup 1.0000x reference)
//
#include <hip/hip_runtime.h>
#include <stdint.h>

// Problem dims
constexpr int NB = 64;     // batch
constexpr int NT = 32;     // time steps
constexpr int NV = 10000;  // vocab
constexpr int NE = 256;    // embed
constexpr int NH = 512;    // hidden

// JAX PRNG mode: 1 = threefry_partitionable (default in jax >= 0.4.30),
// 0 = legacy iota-split counter mode. Flip if sampled region mismatches.
#define PARTITIONABLE 1

// ---------------- persistent device state (re-inited every call) -----------
// g_A[p]: concatenated activations, [k][b] layout: k<NE -> x^T, k>=NE -> h^T
__device__ float g_A[2][(NE + NH) * NB];
__device__ float g_cT[2][NH * NB];
__device__ float g_preact[4 * NH * NB];      // [gate][j][b]
__device__ unsigned int g_keys[2 * NT];      // per-step threefry keys
__device__ unsigned long long g_slots[NT * NB];  // packed argmax per (t,b)
__device__ unsigned int g_tickets[NT];       // last-block tickets

// ---------------- threefry2x32 (exact JAX semantics) -----------------------
__device__ __forceinline__ unsigned int rotl32(unsigned int x, int n) {
  return (x << n) | (x >> (32 - n));
}

__device__ __forceinline__ void threefry2x32(unsigned int k0, unsigned int k1,
                                             unsigned int x0, unsigned int x1,
                                             unsigned int& o0, unsigned int& o1) {
  unsigned int ks0 = k0, ks1 = k1, ks2 = k0 ^ k1 ^ 0x1BD11BDAu;
  const int R0[4] = {13, 15, 26, 6};
  const int R1[4] = {17, 29, 16, 24};
  x0 += ks0; x1 += ks1;
#pragma unroll
  for (int i = 0; i < 5; ++i) {
#pragma unroll
    for (int j = 0; j < 4; ++j) {
      const int r = ((i & 1) == 0) ? R0[j] : R1[j];
      x0 += x1; x1 = rotl32(x1, r); x1 ^= x0;
    }
    const unsigned int inj0 = (i == 0) ? ks1 : (i == 1) ? ks2 : (i == 2) ? ks0
                              : (i == 3) ? ks1 : ks2;
    const unsigned int inj1 = (i == 0) ? ks2 : (i == 1) ? ks0 : (i == 2) ? ks1
                              : (i == 3) ? ks2 : ks0;
    x0 += inj0;
    x1 += inj1 + (unsigned int)(i + 1);
  }
  o0 = x0; o1 = x1;
}

// bits -> uniform(tiny,1) -> gumbel, matching jax._src.random._uniform/_gumbel
__device__ __forceinline__ float gumbel_from_bits(unsigned int bits) {
  float u = __uint_as_float((bits >> 9) | 0x3F800000u) - 1.0f;
  u = (u == 0.0f) ? 1.17549435e-38f : u;
  return -logf(-logf(u));
}

// ---------------- init: keys, state, x0, slots/tickets ---------------------
__global__ void init_kernel(const int* __restrict__ start_tok,
                            const float* __restrict__ emb) {
  const int gtid = blockIdx.x * blockDim.x + threadIdx.x;
  const int stride = gridDim.x * blockDim.x;
  if (gtid < NT) {
    unsigned int o0, o1;
#if PARTITIONABLE
    threefry2x32(0u, 42u, 0u, (unsigned int)gtid, o0, o1);
    g_keys[2 * gtid] = o0; g_keys[2 * gtid + 1] = o1;
#else
    threefry2x32(0u, 42u, (unsigned int)gtid, (unsigned int)(gtid + NT), o0, o1);
    g_keys[gtid] = o0; g_keys[gtid + NT] = o1;  // out[] layout; consumer reads [2t],[2t+1]
#endif
  }
  for (int i = gtid; i < NT * NB; i += stride) g_slots[i] = 0ull;
  for (int i = gtid; i < NT; i += stride) g_tickets[i] = 0u;
  for (int i = gtid; i < NE * NB; i += stride) {
    const int b = i & 63, e = i >> 6;
    const float v = emb[start_tok[b] * NE + e];
    g_A[0][i] = v; g_A[1][i] = v;
  }
  for (int i = gtid; i < NH * NB; i += stride) {
    g_A[0][NE * NB + i] = 0.0f;
    g_cT[0][i] = 0.0f;
  }
}

// ---------------- LSTM pre-activation GEMM ---------------------------------
// grid (64, 4): blockIdx.x = 8-wide j tile, blockIdx.y = gate.
// 4 waves split K=768; lane = b (coalesced A reads, uniform weight rows).
__global__ __launch_bounds__(256) void lstm_kernel(
    int t,
    const float* __restrict__ Wi, const float* __restrict__ Ui,
    const float* __restrict__ Wf, const float* __restrict__ Uf,
    const float* __restrict__ Wog, const float* __restrict__ Uog,
    const float* __restrict__ Wc, const float* __restrict__ Uc) {
  const int tid = threadIdx.x;
  const int lane = tid & 63;
  const int q = tid >> 6;
  const int g = blockIdx.y;
  const int j0 = blockIdx.x * 8;
  const float* W = (g == 0) ? Wi : (g == 1) ? Wf : (g == 2) ? Wog : Wc;
  const float* U = (g == 0) ? Ui : (g == 1) ? Uf : (g == 2) ? Uog : Uc;
  const float* A = g_A[t & 1];

  float acc[8] = {0.f, 0.f, 0.f, 0.f, 0.f, 0.f, 0.f, 0.f};
  const int k0 = q * 192, k1 = k0 + 192;

  // x-part rows (k < NE)
  const int ke = (k1 < NE) ? k1 : NE;
#pragma unroll 2
  for (int k = k0; k < ke; ++k) {
    const float a = A[k * NB + lane];
    const float* wr = W + k * NH + j0;
#pragma unroll
    for (int jj = 0; jj < 8; ++jj) acc[jj] = fmaf(a, wr[jj], acc[jj]);
  }
  // h-part rows (k >= NE)
  const int ks = (k0 > NE) ? k0 : NE;
#pragma unroll 2
  for (int k = ks; k < k1; ++k) {
    const float a = A[k * NB + lane];
    const float* wr = U + (k - NE) * NH + j0;
#pragma unroll
    for (int jj = 0; jj < 8; ++jj) acc[jj] = fmaf(a, wr[jj], acc[jj]);
  }

  __shared__ float ps[4][8][NB];
#pragma unroll
  for (int jj = 0; jj < 8; ++jj) ps[q][jj][lane] = acc[jj];
  __syncthreads();
  if (q == 0) {
#pragma unroll
    for (int jj = 0; jj < 8; ++jj) {
      const float z = ps[0][jj][lane] + ps[1][jj][lane] + ps[2][jj][lane] + ps[3][jj][lane];
      g_preact[(g * NH + j0 + jj) * NB + lane] = z;
    }
  }
}

// ---------------- LSTM gating / state update -------------------------------
__global__ __launch_bounds__(256) void act_kernel(
    int t, const float* __restrict__ bi, const float* __restrict__ bf,
    const float* __restrict__ bog, const float* __restrict__ bc) {
  const int flat = blockIdx.x * 256 + threadIdx.x;  // j*64 + b, < NH*NB
  const int j = flat >> 6;
  const float zi = g_preact[0 * NH * NB + flat] + bi[j];
  const float zf = g_preact[1 * NH * NB + flat] + bf[j];
  const float zo = g_preact[2 * NH * NB + flat] + bog[j];
  const float zc = g_preact[3 * NH * NB + flat] + bc[j];
  const float iv = 1.0f / (1.0f + expf(-zi));
  const float fv = 1.0f / (1.0f + expf(-zf));
  const float ov = 1.0f / (1.0f + expf(-zo));
  const float cc = tanhf(zc);
  const float cold = g_cT[t & 1][flat];
  const float cn = fv * cold + iv * cc;
  g_cT[(t & 1) ^ 1][flat] = cn;
  g_A[(t & 1) ^ 1][NE * NB + flat] = ov * tanhf(cn);
}

// ---------------- logits + gumbel + argmax + finalize ----------------------
// grid (157, 2): x = 64-wide vocab tile, y = 32-wide batch tile.
// Last finishing block (ticket) selects tokens, writes output, gathers x_{t+1}.
__global__ __launch_bounds__(256) void logits_kernel(
    int t, const int* __restrict__ input_x, const int* __restrict__ given_p,
    const float* __restrict__ emb, const float* __restrict__ Wo,
    const float* __restrict__ bo, int* __restrict__ out) {
  __shared__ float hs[NH * 32];  // [k][b_local]
  __shared__ unsigned long long best[32];
  __shared__ int toksh[NB];
  __shared__ int flag;
  const int tid = threadIdx.x;
  const int given = *given_p;
  const int b0 = blockIdx.y * 32;

  if (t >= given) {
    const float* hT = g_A[(t & 1) ^ 1] + NE * NB;
    if (tid < 32) best[tid] = 0ull;
    for (int i = tid; i < NH * 32; i += 256) {
      const int k = i >> 5, bl = i & 31;
      hs[i] = hT[k * NB + b0 + bl];
    }
    __syncthreads();

    const int n = blockIdx.x * 64 + (tid & 15) * 4;
    const int bl = (tid >> 4) * 2;
    const bool nv = (n < NV);
    const int nl = nv ? n : 0;
    float a00 = 0.f, a01 = 0.f, a02 = 0.f, a03 = 0.f;
    float a10 = 0.f, a11 = 0.f, a12 = 0.f, a13 = 0.f;
#pragma unroll 4
    for (int k = 0; k < NH; ++k) {
      const float4 w = *(const float4*)(Wo + k * NV + nl);
      const float2 h2 = *(const float2*)(hs + k * 32 + bl);
      a00 = fmaf(h2.x, w.x, a00); a01 = fmaf(h2.x, w.y, a01);
      a02 = fmaf(h2.x, w.z, a02); a03 = fmaf(h2.x, w.w, a03);
      a10 = fmaf(h2.y, w.x, a10); a11 = fmaf(h2.y, w.y, a11);
      a12 = fmaf(h2.y, w.z, a12); a13 = fmaf(h2.y, w.w, a13);
    }

    if (nv) {
      const unsigned int key0 = g_keys[2 * t], key1 = g_keys[2 * t + 1];
      const float accs[2][4] = {{a00, a01, a02, a03}, {a10, a11, a12, a13}};
#pragma unroll
      for (int s = 0; s < 2; ++s) {
        const int bg = b0 + bl + s;
        unsigned long long bp = 0ull;
#pragma unroll
        for (int jj = 0; jj < 4; ++jj) {
          const int v = n + jj;
          const float logit = accs[s][jj] + bo[v];
          unsigned int u0, u1, bits;
#if PARTITIONABLE
          threefry2x32(key0, key1, 0u, (unsigned int)(bg * NV + v), u0, u1);
          bits = u0 ^ u1;
#else
          const int p = bg * NV + v;
          const unsigned int c = (unsigned int)(p >= (NB / 2) * NV ? p - (NB / 2) * NV : p);
          threefry2x32(key0, key1, c, c + (unsigned int)((NB / 2) * NV), u0, u1);
          bits = (p >= (NB / 2) * NV) ? u1 : u0;
#endif
          const float val = gumbel_from_bits(bits) + logit;
          const unsigned int fb = __float_as_uint(val);
          const unsigned int ord = (fb & 0x80000000u) ? ~fb : (fb | 0x80000000u);
          const unsigned long long pk =
              ((unsigned long long)ord << 32) | (unsigned int)(~v);
          bp = (pk > bp) ? pk : bp;
        }
        atomicMax(&best[bl + s], bp);
      }
    }
    __syncthreads();
    if (tid < 32) atomicMax(&g_slots[t * NB + b0 + tid], best[tid]);
    __threadfence();
  }

  __syncthreads();
  if (tid == 0) {
    const unsigned int old = atomicAdd(&g_tickets[t], 1u);
    flag = (old == gridDim.x * gridDim.y - 1) ? 1 : 0;
  }
  __syncthreads();

  if (flag) {
    __threadfence();  // acquire: see all other blocks' slot updates
    if (tid < NB) {
      int tok;
      if (t < given) {
        tok = input_x[tid * NT + t];
      } else {
        const unsigned long long pk = g_slots[t * NB + tid];
        tok = (int)(~(unsigned int)(pk & 0xFFFFFFFFull));
      }
      out[tid * NT + t] = tok;
      toksh[tid] = tok;
    }
    __syncthreads();
    for (int i = tid; i < NB * NE; i += 256) {
      const int b = i & 63, e = i >> 6;
      const float v = emb[toksh[b] * NE + e];
      g_A[0][i] = v;  // x lives in both parity buffers
      g_A[1][i] = v;
    }
  }
}

// ---------------- host launch ----------------------------------------------
extern "C" void kernel_launch(void* const* d_in, const int* in_sizes, int n_in,
                              void* d_out, int out_size, void* d_ws, size_t ws_size,
                              hipStream_t stream) {
  const int* input_x = (const int*)d_in[0];
  const int* given_num = (const int*)d_in[1];
  const int* start_tok = (const int*)d_in[2];
  const float* emb = (const float*)d_in[3];
  const float* Wi = (const float*)d_in[4];
  const float* Ui = (const float*)d_in[5];
  const float* bi = (const float*)d_in[6];
  const float* Wf = (const float*)d_in[7];
  const float* Uf = (const float*)d_in[8];
  const float* bf = (const float*)d_in[9];
  const float* Wog = (const float*)d_in[10];
  const float* Uog = (const float*)d_in[11];
  const float* bog = (const float*)d_in[12];
  const float* Wc = (const float*)d_in[13];
  const float* Uc = (const float*)d_in[14];
  const float* bc = (const float*)d_in[15];
  const float* Wo = (const float*)d_in[16];
  const float* bo = (const float*)d_in[17];
  int* out = (int*)d_out;

  init_kernel<<<128, 256, 0, stream>>>(start_tok, emb);
  for (int t = 0; t < NT; ++t) {
    lstm_kernel<<<dim3(64, 4), 256, 0, stream>>>(t, Wi, Ui, Wf, Uf, Wog, Uog, Wc, Uc);
    act_kernel<<<128, 256, 0, stream>>>(t, bi, bf, bog, bc);
    logits_kernel<<<dim3(157, 2), 256, 0, stream>>>(t, input_x, given_num, emb, Wo, bo, out);
  }
}